// Round 1
// baseline (311.730 us; speedup 1.0000x reference)
//
#include <hip/hip_runtime.h>

#define NN 2048
#define DD 128
#define EE 16384
#define TWOE (2 * EE)   // floats per output row = 32768

typedef float v4f __attribute__((ext_vector_type(4)));

// ---------------------------------------------------------------------------
// Stage 1: u[d] = sum_k W2[0, D+k] * W1[k, d]  (only surviving part of W1/W2
// after softmax cancellation: weight[i,j] = s_i[i]+s_j[j]; s_i is constant per
// row and cancels in the row-softmax). Then e[n] = exp(X_n[n,:] . u).
// ---------------------------------------------------------------------------
__global__ void k_sj(const float* __restrict__ X, const float* __restrict__ W1,
                     const float* __restrict__ W2, float* __restrict__ ev) {
    __shared__ float u[DD];
    const int t = threadIdx.x;  // 256
    if (t < DD) {
        float acc = 0.f;
#pragma unroll 8
        for (int k = 0; k < DD; ++k) acc += W2[DD + k] * W1[k * DD + t];
        u[t] = acc;
    }
    __syncthreads();
    const int wave = t >> 6, lane = t & 63;
    const int row0 = blockIdx.x * 16 + wave * 4;
#pragma unroll
    for (int rr = 0; rr < 4; ++rr) {
        const int row = row0 + rr;
        const float2 v = ((const float2*)(X + (size_t)row * DD))[lane];
        float acc = v.x * u[2 * lane] + v.y * u[2 * lane + 1];
#pragma unroll
        for (int off = 32; off; off >>= 1) acc += __shfl_down(acc, off);
        if (lane == 0) ev[row] = expf(acc);
    }
}

// ---------------------------------------------------------------------------
// Stage 2 (fused): block i
//   (a) computes Z[i] = sum_j adj[i,j] * e[j]   (adj is {0,1})
//   (b) zeroes output row i (plain float4 stores — the rocclr-fill-proven
//       6.4 TB/s path; 32 stores/thread amortizes per-block overhead).
// The 16 MB adj read hides under the 268 MB output fill.
// ---------------------------------------------------------------------------
__global__ __launch_bounds__(256) void k_zero_z(const int* __restrict__ adj,
                                                const float* __restrict__ ev,
                                                float* __restrict__ Zv,
                                                float* __restrict__ out) {
    const int i = blockIdx.x;
    const int t = threadIdx.x;  // 256

    // --- Z[i]: issue the loads first so their latency hides under the fill
    const int4*   arow = (const int4*)(adj + (size_t)i * NN);
    const float4* ef   = (const float4*)ev;
    float acc = 0.f;
#pragma unroll
    for (int b = 0; b < NN / 4; b += 256) {
        const int4   a  = arow[b + t];
        const float4 e4 = ef[b + t];
        acc += (float)a.x * e4.x + (float)a.y * e4.y +
               (float)a.z * e4.z + (float)a.w * e4.w;
    }

    // --- zero row i: 8192 float4, 32 per thread, wave-contiguous
    v4f z4 = {0.f, 0.f, 0.f, 0.f};
    v4f* orow = (v4f*)(out + (size_t)i * TWOE);
#pragma unroll
    for (int b = 0; b < TWOE / 4; b += 256)
        orow[b + t] = z4;

    // --- reduce Z
#pragma unroll
    for (int off = 32; off; off >>= 1) acc += __shfl_down(acc, off);
    __shared__ float wsum[4];
    if ((t & 63) == 0) wsum[t >> 6] = acc;
    __syncthreads();
    if (t == 0) Zv[i] = wsum[0] + wsum[1] + wsum[2] + wsum[3];
}

// ---------------------------------------------------------------------------
// Stage 3: direct scatter of the 2E nonzeros into the zeroed output.
// Column c<E  : out[dst[c], c]     = attention[dst,src]
// Column c>=E : out[src[c], c]     = attention[src,dst]
// attention[i,j] = Z[i]==0 ? 1/N : (adj[i,j] ? e[j]/Z[i] : 0)
// c is the column index, so each (row,col) has exactly one writer.
// ---------------------------------------------------------------------------
__global__ void k_scatter(const int* __restrict__ ei, const int* __restrict__ adj,
                          const float* __restrict__ ev, const float* __restrict__ Zv,
                          float* __restrict__ out) {
    const int e = blockIdx.x * blockDim.x + threadIdx.x;
    if (e >= EE) return;
    const int s = ei[e];        // edge_indices[0] = src
    const int d = ei[EE + e];   // edge_indices[1] = dst
    const float invn = 1.0f / (float)NN;

    const float zd = Zv[d];
    float ap;
    if (zd == 0.f) ap = invn;
    else ap = (adj[(size_t)d * NN + s] > 0) ? ev[s] / zd : 0.f;

    const float zs = Zv[s];
    float ac;
    if (zs == 0.f) ac = invn;
    else ac = (adj[(size_t)s * NN + d] > 0) ? ev[d] / zs : 0.f;

    out[(size_t)d * TWOE + e]      = ap;
    out[(size_t)s * TWOE + EE + e] = ac;
}

extern "C" void kernel_launch(void* const* d_in, const int* in_sizes, int n_in,
                              void* d_out, int out_size, void* d_ws, size_t ws_size,
                              hipStream_t stream) {
    const float* X   = (const float*)d_in[0];
    const int*   ei  = (const int*)d_in[1];
    const int*   adj = (const int*)d_in[2];
    const float* W1  = (const float*)d_in[3];
    const float* W2  = (const float*)d_in[4];

    float* ev = (float*)d_ws;   // [2048]  e[j] = exp(s_j[j])
    float* Zv = ev + NN;        // [2048]

    float* out = (float*)d_out;

    k_sj      <<<NN / 16,  256, 0, stream>>>(X, W1, W2, ev);
    k_zero_z  <<<NN,       256, 0, stream>>>(adj, ev, Zv, out);
    k_scatter <<<EE / 256, 256, 0, stream>>>(ei, adj, ev, Zv, out);
}

// Round 2
// 263.349 us; speedup vs baseline: 1.1837x; 1.1837x over previous
//
#include <hip/hip_runtime.h>

#define NN 2048
#define DD 128
#define EE 16384
#define TWOE (2 * EE)   // floats per output row = 32768

// ---------------------------------------------------------------------------
// Stage 1: u[d] = sum_k W2[0, D+k] * W1[k, d]  (only surviving part of W1/W2
// after softmax cancellation: weight[i,j] = s_i[i]+s_j[j]; s_i is constant per
// row and cancels in the row-softmax). Then e[n] = exp(X_n[n,:] . u).
// ---------------------------------------------------------------------------
__global__ void k_sj(const float* __restrict__ X, const float* __restrict__ W1,
                     const float* __restrict__ W2, float* __restrict__ ev) {
    __shared__ float u[DD];
    const int t = threadIdx.x;  // 256
    if (t < DD) {
        float acc = 0.f;
#pragma unroll 8
        for (int k = 0; k < DD; ++k) acc += W2[DD + k] * W1[k * DD + t];
        u[t] = acc;
    }
    __syncthreads();
    const int wave = t >> 6, lane = t & 63;
    const int row0 = blockIdx.x * 16 + wave * 4;
#pragma unroll
    for (int rr = 0; rr < 4; ++rr) {
        const int row = row0 + rr;
        const float2 v = ((const float2*)(X + (size_t)row * DD))[lane];
        float acc = v.x * u[2 * lane] + v.y * u[2 * lane + 1];
#pragma unroll
        for (int off = 32; off; off >>= 1) acc += __shfl_down(acc, off);
        if (lane == 0) ev[row] = expf(acc);
    }
}

// ---------------------------------------------------------------------------
// Stage 2: Z[i] = sum_j adj[i,j] * e[j]   (adj is {0,1}: multiply, no branch).
// 16 MB adj read, ~3 us. The output zeroing is done by hipMemsetAsync (the
// rocclr fillBuffer path, proven 6.15-6.47 TB/s in this harness's profile).
// ---------------------------------------------------------------------------
__global__ void k_rowz(const int* __restrict__ adj, const float* __restrict__ ev,
                       float* __restrict__ Zv) {
    const int i = blockIdx.x;
    const int t = threadIdx.x;  // 256
    const int4*   arow = (const int4*)(adj + (size_t)i * NN);
    const float4* ef   = (const float4*)ev;
    float acc = 0.f;
#pragma unroll
    for (int b = 0; b < NN / 4; b += 256) {
        const int4   a  = arow[b + t];
        const float4 e4 = ef[b + t];
        acc += (float)a.x * e4.x + (float)a.y * e4.y +
               (float)a.z * e4.z + (float)a.w * e4.w;
    }
#pragma unroll
    for (int off = 32; off; off >>= 1) acc += __shfl_down(acc, off);
    __shared__ float wsum[4];
    if ((t & 63) == 0) wsum[t >> 6] = acc;
    __syncthreads();
    if (t == 0) Zv[i] = wsum[0] + wsum[1] + wsum[2] + wsum[3];
}

// ---------------------------------------------------------------------------
// Stage 3: direct scatter of the 2E nonzeros into the zeroed output.
// Column c<E  : out[dst[c], c]     = attention[dst,src]
// Column c>=E : out[src[c], c+E]   = attention[src,dst]
// attention[i,j] = Z[i]==0 ? 1/N : (adj[i,j] ? e[j]/Z[i] : 0)
// c is the column index, so each (row,col) has exactly one writer.
// ---------------------------------------------------------------------------
__global__ void k_scatter(const int* __restrict__ ei, const int* __restrict__ adj,
                          const float* __restrict__ ev, const float* __restrict__ Zv,
                          float* __restrict__ out) {
    const int e = blockIdx.x * blockDim.x + threadIdx.x;
    if (e >= EE) return;
    const int s = ei[e];        // edge_indices[0] = src
    const int d = ei[EE + e];   // edge_indices[1] = dst
    const float invn = 1.0f / (float)NN;

    const float zd = Zv[d];
    float ap;
    if (zd == 0.f) ap = invn;
    else ap = (adj[(size_t)d * NN + s] > 0) ? ev[s] / zd : 0.f;

    const float zs = Zv[s];
    float ac;
    if (zs == 0.f) ac = invn;
    else ac = (adj[(size_t)s * NN + d] > 0) ? ev[d] / zs : 0.f;

    out[(size_t)d * TWOE + e]      = ap;
    out[(size_t)s * TWOE + EE + e] = ac;
}

extern "C" void kernel_launch(void* const* d_in, const int* in_sizes, int n_in,
                              void* d_out, int out_size, void* d_ws, size_t ws_size,
                              hipStream_t stream) {
    const float* X   = (const float*)d_in[0];
    const int*   ei  = (const int*)d_in[1];
    const int*   adj = (const int*)d_in[2];
    const float* W1  = (const float*)d_in[3];
    const float* W2  = (const float*)d_in[4];

    float* ev = (float*)d_ws;   // [2048]  e[j] = exp(s_j[j])
    float* Zv = ev + NN;        // [2048]

    float* out = (float*)d_out;

    // Zero the full [N, 2E] output via the rocclr fill path (max proven BW).
    // Graph-capturable async op on the provided stream (no sync APIs).
    hipMemsetAsync(out, 0, (size_t)out_size, stream);

    k_sj      <<<NN / 16,  256, 0, stream>>>(X, W1, W2, ev);
    k_rowz    <<<NN,       256, 0, stream>>>(adj, ev, Zv);
    k_scatter <<<EE / 256, 256, 0, stream>>>(ei, adj, ev, Zv, out);
}